// Round 9
// baseline (206.296 us; speedup 1.0000x reference)
//
#include <hip/hip_runtime.h>
#include <hip/hip_fp16.h>

// AudioStructuralAnalyzer fused kernel, round 11.
// vs round 10 (112 us, VALUBusy 57.6%, barriers proven non-bottleneck):
//  Theory: jointly issue-limited on VALU + LDS pipes (~280 LDS instr/thread).
//  - Phase B: even-pair items (r,2m)+(r,2m+1). 6 aligned ds_read_b64 replace
//    18 ds_read_b32; sobel column sums c_k = x2k-x0k, s_k = x0k+2x1k+x2k
//    computed once for 4 columns, reused by both items (f32 reassociation
//    only). Index math halves. 38 cols = exactly 19 pairs.
//  - Phase C: even pairs. 9 ds_read_b64 replace 16 ds_read_b32; lcol sums
//    shared with BIT-IDENTICAL pk-op order (hadd2 then hfma2). 18 pairs exact.
//  - Everything else (vpasses, D23/D45/D6, LDS layout 37824 B, launch
//    bounds (512,4)) byte-identical to round 10.
// Cuts ~25% of LDS issue and ~6% of VALU -> predict ~100-106 us dispatch.

#define F_DIM 256
#define T_DIM 2048
#define B_DIM 8
#define C_DIM 2
#define TILE  32
#define NTHR  512

#define XROWS 40          // x tile: halo 4
#define XS    40          // even stride (float2 loads stay aligned)
#define UROWS 38          // (ux,uy): halo 3
#define US    40          // stored with +1 col shift: u(r,cc) at word r*US+cc+1
#define FROWS 36          // field tiles: halo 2
#define FS    36
#define FH2   18          // FS/2 uint2 pairs per row
#define EPSF  1e-10f

template<bool V> struct BoolC { static constexpr bool value = V; };

static __device__ __forceinline__ __half2 pack_h2(float a, float b) {
    auto v = __builtin_amdgcn_cvt_pkrtz(a, b);   // v_cvt_pkrtz_f16_f32, 1 inst
    return *(__half2*)&v;
}
static __device__ __forceinline__ float clamp01(float x) {
    return fminf(fmaxf(x, 0.f), 1.f);
}

__global__ __launch_bounds__(512, 4)
void audio_struct_fused(const float* __restrict__ x_in,
                        const float* __restrict__ gk_in,
                        float* __restrict__ out)
{
    __shared__ __align__(16) float   s_x [XROWS*XS];    // 6400 B
    __shared__ __align__(16) __half2 s_u [UROWS*US];    // 6080 B (ux,uy), col-shifted
    __shared__ __align__(16) __half2 s_P0[FROWS*FS];    // 5184 B (trace,diff) -> (sf,cv)v
    __shared__ __align__(16) __half2 s_P1[FROWS*FS];    // 5184 B (sxy,tin) -> (ux,uy)v
    __shared__ __align__(16) __half2 s_P2[FROWS*FS];    // 5184 B (sf,cv)
    __shared__ __align__(16) __half2 s_P3[FROWS*FS];    // 5184 B (sxy,tin)v
    __shared__ __align__(16) float   s_tmp[TILE*FS];    // 4608 B (trace,diff)v -> x^2 v
    // total 37824 B -> 4 blocks/CU x 8 waves = 32 waves/CU cap

    const int tx  = threadIdx.x;          // 0..31 (time)
    const int ty  = threadIdx.y;          // 0..15 (freq)
    const int tid = ty * 32 + tx;         // 0..511
    const int t0  = blockIdx.x * TILE;
    const int f0  = blockIdx.y * TILE;
    const int b   = blockIdx.z;

    // 1D gaussian = normalized middle row of the separable 5x5 kernel
    float r0 = gk_in[10], r1 = gk_in[11], r2 = gk_in[12], r3 = gk_in[13], r4 = gk_in[14];
    float winv = __builtin_amdgcn_rcpf(r0 + r1 + r2 + r3 + r4);
    const float w[5] = {r0*winv, r1*winv, r2*winv, r3*winv, r4*winv};
    const __half2 wh2[5] = {pack_h2(w[0],w[0]), pack_h2(w[1],w[1]), pack_h2(w[2],w[2]),
                            pack_h2(w[3],w[3]), pack_h2(w[4],w[4])};
    const __half2 h2z    = pack_h2(0.f, 0.f);
    const __half2 two    = pack_h2(2.f, 2.f);
    const __half2 eighth = pack_h2(0.125f, 0.125f);

    // paired pk vertical pass: dst[idx] = sum_i w[i]*src[idx + i*FH2] (uint2 lanes)
    auto vpass_pair = [&](const __half2* src, __half2* dst) {
        const uint2* s = (const uint2*)src;
        uint2* d = (uint2*)dst;
        for (int idx = tid; idx < TILE * FH2; idx += NTHR) {
            __half2 a0 = h2z, a1 = h2z;
            #pragma unroll
            for (int i = 0; i < 5; ++i) {
                uint2 v = s[idx + i * FH2];
                a0 = __hfma2(wh2[i], *(const __half2*)&v.x, a0);
                a1 = __hfma2(wh2[i], *(const __half2*)&v.y, a1);
            }
            uint2 o; o.x = *(const unsigned*)&a0; o.y = *(const unsigned*)&a1;
            d[idx] = o;
        }
    };

    float acc[6][2];
    #pragma unroll
    for (int k = 0; k < 6; ++k)
        #pragma unroll
        for (int s = 0; s < 2; ++s) acc[k][s] = 0.0f;

    const bool interior = (f0 >= 4) && (f0 + TILE + 4 <= F_DIM) &&
                          (t0 >= 4) && (t0 + TILE + 4 <= T_DIM);

    // ---- Phases A, B, CD1 templated on interior fast path ----
    auto phaseABC = [&](const float* xp, auto FASTC) {
        constexpr bool FAST = decltype(FASTC)::value;

        // ---- Phase A: load x tile + halo 4 (float2, never straddles edges) ----
        for (int idx = tid; idx < XROWS * 20; idx += NTHR) {
            int r  = idx / 20, c2 = idx - r * 20;
            float2 v;
            if (FAST) {
                v = *(const float2*)(xp + (size_t)(f0 + r - 4) * T_DIM + (t0 + c2 * 2 - 4));
            } else {
                int gf = f0 + r - 4;
                int gt = t0 + c2 * 2 - 4;
                v = make_float2(0.f, 0.f);
                if ((unsigned)gf < (unsigned)F_DIM && (unsigned)gt < (unsigned)T_DIM)
                    v = *(const float2*)(xp + (size_t)gf * T_DIM + gt);
            }
            *(float2*)&s_x[r * XS + c2 * 2] = v;
        }
        __syncthreads();

        // ---- Phase B: even-pair items (r,2m)+(r,2m+1); 38x38 u, 36x36 fields ----
        for (int q = tid; q < UROWS * 19; q += NTHR) {
            int r = q / 19, m = q - r * 19;
            const float2* x2p = (const float2*)s_x;
            int base = r * (XS/2) + m;
            // rows r..r+2, cols 2m..2m+3 (cols: [0]=a.x [1]=a.y [2]=b.x [3]=b.y)
            float2 a0 = x2p[base],            b0 = x2p[base + 1];
            float2 a1 = x2p[base + (XS/2)],   b1 = x2p[base + (XS/2) + 1];
            float2 a2 = x2p[base + XS],       b2 = x2p[base + XS + 1];
            // shared sobel column sums
            float c0 = a2.x - a0.x, c1 = a2.y - a0.y;
            float c2c = b2.x - b0.x, c3 = b2.y - b0.y;
            float s0 = fmaf(2.f, a1.x, a0.x + a2.x);
            float s1 = fmaf(2.f, a1.y, a0.y + a2.y);
            float s2 = fmaf(2.f, b1.x, b0.x + b2.x);
            float s3 = fmaf(2.f, b1.y, b0.y + b2.y);
            // item A (cc=2m), item B (cc=2m+1)
            float gfvA = (fmaf(2.f, c1, c0) + c2c) * 0.125f;
            float gtvA = (s2 - s0) * 0.125f;
            float gfvB = (fmaf(2.f, c2c, c1) + c3) * 0.125f;
            float gtvB = (s3 - s1) * 0.125f;

            bool rin = (r >= 1) && (r < UROWS - 1);
            int  fiA = (r - 1) * FS + 2 * m - 1;
            int  gfr = f0 + r - 3;
            bool frOK = FAST || ((unsigned)gfr < (unsigned)F_DIM);

            #pragma unroll
            for (int jj = 0; jj < 2; ++jj) {
                float gfv = jj ? gfvB : gfvA;
                float gtv = jj ? gtvB : gtvA;
                int   ccI = 2 * m + jj;
                bool  okI = true;
                if (!FAST) {
                    int gtc = t0 + ccI - 3;
                    okI = frOK & ((unsigned)gtc < (unsigned)T_DIM);
                }
                float ux = 0.f, uy = 0.f, trp = 0.f, dfp = 0.f, sxy = 0.f,
                      tin = 0.f, sf = 0.f;
                if (okI) {
                    float gte = gtv + EPSF;
                    float g2f = gfv * gfv;
                    float d2  = fmaf(gte, gte, g2f);
                    float rh  = __builtin_amdgcn_rsqf(d2);
                    ux = gte * rh;                  // cos(atan2(gf, gt+eps))
                    uy = gfv * rh;                  // sin(atan2(gf, gt+eps))
                    float m2 = fmaf(gtv, gtv, g2f) + EPSF;
                    trp = m2;
                    dfp = m2 * (ux - uy) * (ux + uy);
                    sxy = m2 * ux * uy;
                    tin = __builtin_amdgcn_rcpf(1.0f + fabsf(gtv));
                    sf  = fabsf(gfv);
                }
                s_u[r * US + ccI + 1] = pack_h2(ux, uy);   // +1 col shift
                bool pv = rin && (jj ? (m <= 17) : (m >= 1));
                if (pv) {
                    int fi = fiA + jj;
                    s_P0[fi] = pack_h2(trp, dfp);
                    s_P1[fi] = pack_h2(sxy, tin);
                    s_P2[fi] = pack_h2(sf, 0.f);   // .y = cv, filled in Phase C
                }
            }
        }
        __syncthreads();

        // ---- Slot CD1: Phase C pairs (u sobel -> P2.y) + v(P0->tmp) + v(P1->P3) ----
        for (int q = tid; q < FROWS * 18; q += NTHR) {
            int r = q / 18, m = q - r * 18;
            const uint2* su2 = (const uint2*)s_u;
            int base = r * (US/2) + m;     // u word 2m at row r
            // rows r..r+2, u words 2m..2m+5 (rel 0..5); A uses rel 1..3, B rel 2..4
            uint2 q00 = su2[base],              q01 = su2[base + 1],              q02 = su2[base + 2];
            uint2 q10 = su2[base + (US/2)],     q11 = su2[base + (US/2) + 1],     q12 = su2[base + (US/2) + 2];
            uint2 q20 = su2[base + US],         q21 = su2[base + US + 1],         q22 = su2[base + US + 2];
            #define H2(v) (*(const __half2*)&(v))
            // shared vertical (1,2,1) column sums for rel cols 1..4
            __half2 l1 = __hadd2(H2(q00.y), H2(q20.y)); l1 = __hfma2(two, H2(q10.y), l1);
            __half2 l2 = __hadd2(H2(q01.x), H2(q21.x)); l2 = __hfma2(two, H2(q11.x), l2);
            __half2 l3 = __hadd2(H2(q01.y), H2(q21.y)); l3 = __hfma2(two, H2(q11.y), l3);
            __half2 l4 = __hadd2(H2(q02.x), H2(q22.x)); l4 = __hfma2(two, H2(q12.x), l4);
            // horizontal (1,2,1) row sums, per item
            __half2 tA = __hadd2(H2(q00.y), H2(q01.y)); tA = __hfma2(two, H2(q01.x), tA);
            __half2 bA = __hadd2(H2(q20.y), H2(q21.y)); bA = __hfma2(two, H2(q21.x), bA);
            __half2 tB = __hadd2(H2(q01.x), H2(q02.x)); tB = __hfma2(two, H2(q01.y), tB);
            __half2 bB = __hadd2(H2(q21.x), H2(q22.x)); bB = __hfma2(two, H2(q21.y), bB);
            #undef H2
            __half2 dxA = __hmul2(__hsub2(l3, l1), eighth);
            __half2 dyA = __hmul2(__hsub2(bA, tA), eighth);
            __half2 dxB = __hmul2(__hsub2(l4, l2), eighth);
            __half2 dyB = __hmul2(__hsub2(bB, tB), eighth);

            int gfr = f0 + r - 2;
            bool frOK = FAST || ((unsigned)gfr < (unsigned)F_DIM);
            #pragma unroll
            for (int jj = 0; jj < 2; ++jj) {
                float2 fx = __half22float2(jj ? dxB : dxA);
                float2 fy = __half22float2(jj ? dyB : dyA);
                float cv = __builtin_amdgcn_sqrtf(
                    fmaf(fx.x, fx.x, fmaf(fx.y, fx.y,
                    fmaf(fy.x, fy.x, fy.y * fy.y))) + EPSF);
                int ccI = 2 * m + jj;
                if (!FAST) {
                    int gtc = t0 + ccI - 2;
                    if (!(frOK & ((unsigned)gtc < (unsigned)T_DIM))) cv = 0.f;
                }
                ((__half*)s_P2)[2 * (r * FS + ccI) + 1] = __float2half_rn(cv);
            }
        }
        vpass_pair(s_P0, (__half2*)s_tmp);   // j0 vertical: (trace,diff)
        vpass_pair(s_P1, s_P3);              // j1 vertical: (sxy,tin)
        __syncthreads();
    };

    for (int c = 0; c < C_DIM; ++c) {
        if (c) __syncthreads();   // protect LDS reuse (c==1 only)

        const float* xp = x_in + (size_t)(b * C_DIM + c) * F_DIM * T_DIM;
        if (interior) phaseABC(xp, BoolC<true>{});
        else          phaseABC(xp, BoolC<false>{});

        __half2* tmp_h2 = (__half2*)s_tmp;

        // ====== Slot D23: j0h + j1h + entropy/temporal ; v(P2->P0) ; v(u->P1) ======
        {
            float trace_s[2], diff_s[2];
            #pragma unroll
            for (int s = 0; s < 2; ++s) {
                int ry = ty + 16 * s;
                float a = 0.f, bv = 0.f;
                #pragma unroll
                for (int j = 0; j < 5; ++j) {
                    float2 v = __half22float2(tmp_h2[ry * FS + tx + j]);
                    a += w[j] * v.x; bv += w[j] * v.y;
                }
                trace_s[s] = a; diff_s[s] = bv;
            }
            #pragma unroll
            for (int s = 0; s < 2; ++s) {
                int ry = ty + 16 * s;
                __half2 a = h2z;
                #pragma unroll
                for (int j = 0; j < 5; ++j)
                    a = __hfma2(wh2[j], s_P3[ry * FS + tx + j], a);
                float2 v = __half22float2(a);          // (vxy_s, tp)
                float trace = trace_s[s], diff = diff_s[s];
                float disc  = __builtin_amdgcn_sqrtf(
                                  fmaxf(diff * diff + 4.f * v.x * v.x, 0.f) + EPSF);
                float l1 = fmaxf(0.5f * (trace + disc), EPSF);
                float l2 = fmaxf(0.5f * (trace - disc), EPSF);
                float inv = __builtin_amdgcn_rcpf(l1 + l2 + EPSF);
                float p1 = l1 * inv, p2 = l2 * inv;
                // v_log_f32 IS log2 — matches reference's ln(p)/ln(2)
                float ent = -(p1 * __builtin_amdgcn_logf(p1 + EPSF)
                            + p2 * __builtin_amdgcn_logf(p2 + EPSF));
                acc[0][s] += 0.5f * clamp01(ent);
                acc[4][s] += 0.5f * clamp01(v.y);
            }
            vpass_pair(s_P2, s_P0);          // j2 vertical: (sf,cv) -> P0
            {
                // j3 vertical: u -> P1.  u(r+i+1, cc+1), cc = 2p,2p+1
                // -> word (r+i+1)*US + 2 + 2p: uint2-aligned
                const uint2* su2 = (const uint2*)s_u;
                uint2* dP1 = (uint2*)s_P1;
                for (int idx = tid; idx < TILE * FH2; idx += NTHR) {
                    int r = idx / FH2, p = idx - r * FH2;
                    const uint2* sp = su2 + (r + 1) * (US/2) + 1 + p;
                    __half2 a0 = h2z, a1 = h2z;
                    #pragma unroll
                    for (int i = 0; i < 5; ++i) {
                        uint2 v = sp[i * (US/2)];
                        a0 = __hfma2(wh2[i], *(const __half2*)&v.x, a0);
                        a1 = __hfma2(wh2[i], *(const __half2*)&v.y, a1);
                    }
                    uint2 o; o.x = *(const unsigned*)&a0; o.y = *(const unsigned*)&a1;
                    dP1[idx] = o;
                }
            }
        }
        __syncthreads();

        // ====== Slot D45: j2h (P0) + j3h (P1) ; v(x^2 -> tmp) ======
        #pragma unroll
        for (int s = 0; s < 2; ++s) {
            int ry = ty + 16 * s;
            __half2 a = h2z;
            #pragma unroll
            for (int j = 0; j < 5; ++j)
                a = __hfma2(wh2[j], s_P0[ry * FS + tx + j], a);
            float2 v = __half22float2(a);          // (sp, cvs)
            acc[5][s] += 0.5f * clamp01(v.x);
            acc[2][s] += 0.5f * v.y;
        }
        #pragma unroll
        for (int s = 0; s < 2; ++s) {
            int ry = ty + 16 * s;
            __half2 a = h2z;
            #pragma unroll
            for (int j = 0; j < 5; ++j)
                a = __hfma2(wh2[j], s_P1[ry * FS + tx + j], a);
            float2 v = __half22float2(a);          // (ua, va)
            acc[1][s] += 0.5f * clamp01(
                __builtin_amdgcn_sqrtf(v.x * v.x + v.y * v.y + EPSF));
        }
        {
            // j4 vertical: x(r+i+2, cc+2), cc = 2p,2p+1
            // -> word (r+i+2)*XS + 2 + 2p: float2-aligned
            const float2* sx2 = (const float2*)s_x;
            float2* dt2 = (float2*)s_tmp;
            for (int idx = tid; idx < TILE * FH2; idx += NTHR) {
                int r = idx / FH2, p = idx - r * FH2;
                const float2* sp = sx2 + (r + 2) * (XS/2) + 1 + p;
                float a = 0.f, bv = 0.f;
                #pragma unroll
                for (int i = 0; i < 5; ++i) {
                    float2 v = sp[i * (XS/2)];
                    a  = fmaf(w[i], v.x * v.x, a);
                    bv = fmaf(w[i], v.y * v.y, bv);
                }
                dt2[idx] = make_float2(a, bv);
            }
        }
        __syncthreads();

        // ====== Slot D6: j4h (le) + harmonic epilogue (no trailing barrier) ======
        #pragma unroll
        for (int s = 0; s < 2; ++s) {
            int ry = ty + 16 * s;
            float le = 0.f;
            #pragma unroll
            for (int j = 0; j < 5; ++j)
                le += w[j] * s_tmp[ry * FS + tx + j];
            float xm  = s_x[(ry + 1) * XS + tx + 4];
            float x0v = s_x[(ry + 4) * XS + tx + 4];
            float xpv = s_x[(ry + 7) * XS + tx + 4];
            float harm = fabsf(2.f * x0v - xm - xpv);
            acc[3][s] += 0.5f * clamp01(harm * __builtin_amdgcn_rcpf(le + EPSF));
        }
    }

    // ---- write 6 output planes, coalesced ----
    const size_t plane = (size_t)B_DIM * F_DIM * T_DIM;
    const size_t base  = (size_t)b * F_DIM * T_DIM + (size_t)f0 * T_DIM + t0 + tx;
    #pragma unroll
    for (int k = 0; k < 6; ++k)
        #pragma unroll
        for (int s = 0; s < 2; ++s)
            out[k * plane + base + (size_t)(ty + 16 * s) * T_DIM] = acc[k][s];
}

extern "C" void kernel_launch(void* const* d_in, const int* in_sizes, int n_in,
                              void* d_out, int out_size, void* d_ws, size_t ws_size,
                              hipStream_t stream) {
    const float* x  = (const float*)d_in[0];
    const float* gk = (const float*)d_in[1];
    float* out = (float*)d_out;
    dim3 grid(T_DIM / TILE, F_DIM / TILE, B_DIM);   // 64 x 8 x 8 = 4096 blocks
    dim3 block(32, 16);                             // 512 threads = 8 waves
    audio_struct_fused<<<grid, block, 0, stream>>>(x, gk, out);
}

// Round 10
// 201.955 us; speedup vs baseline: 1.0215x; 1.0215x over previous
//
#include <hip/hip_runtime.h>
#include <hip/hip_fp16.h>

// AudioStructuralAnalyzer fused kernel, round 12.
// vs round 11 (111.6 us, VALUBusy 51.9%): model revised — LDS-pipe-THROUGHPUT
// bound (~234 LDS inst/thread ≈ 90 us of per-CU LDS issue; VALU/barrier/
// occupancy levers all measured flat). This round cuts LDS ops ~35% by
// sharing conv taps:
//  - horizontal passes: col-pair threads (ry=tid>>4, mc=tid&15) — 5-tap
//    window of 2 adjacent cols = 6 h2 = 3 ds_read_b64 (was 10 ds_read_b32).
//    D2/D3/D45/D6 + epilogues + float2 output store.
//  - vertical passes: row-pair items (288 items × 2 rows) — 6 reads + 2
//    writes per 2 rows (was 12). Idle threads issue no LDS ops (throughput
//    bound -> only total op count matters).
//  - Phases A/B/C, slots, barriers, launch config unchanged from round 11.
// Per-output arithmetic order preserved -> absmax stays 0.00390625.

#define F_DIM 256
#define T_DIM 2048
#define B_DIM 8
#define C_DIM 2
#define TILE  32
#define NTHR  512

#define XROWS 40          // x tile: halo 4
#define XS    40          // even stride (float2 loads stay aligned)
#define UROWS 38          // (ux,uy): halo 3
#define US    40          // stored with +1 col shift: u(r,cc) at word r*US+cc+1
#define FROWS 36          // field tiles: halo 2
#define FS    36
#define FH2   18          // FS/2 uint2 pairs per row
#define EPSF  1e-10f

template<bool V> struct BoolC { static constexpr bool value = V; };

static __device__ __forceinline__ __half2 pack_h2(float a, float b) {
    auto v = __builtin_amdgcn_cvt_pkrtz(a, b);   // v_cvt_pkrtz_f16_f32, 1 inst
    return *(__half2*)&v;
}
static __device__ __forceinline__ float clamp01(float x) {
    return fminf(fmaxf(x, 0.f), 1.f);
}
static __device__ __forceinline__ __half2 u2h(unsigned v) {
    return *(const __half2*)&v;
}

__global__ __launch_bounds__(512, 4)
void audio_struct_fused(const float* __restrict__ x_in,
                        const float* __restrict__ gk_in,
                        float* __restrict__ out)
{
    __shared__ __align__(16) float   s_x [XROWS*XS];    // 6400 B
    __shared__ __align__(16) __half2 s_u [UROWS*US];    // 6080 B (ux,uy), col-shifted
    __shared__ __align__(16) __half2 s_P0[FROWS*FS];    // 5184 B (trace,diff) -> (sf,cv)v
    __shared__ __align__(16) __half2 s_P1[FROWS*FS];    // 5184 B (sxy,tin) -> (ux,uy)v
    __shared__ __align__(16) __half2 s_P2[FROWS*FS];    // 5184 B (sf,cv)
    __shared__ __align__(16) __half2 s_P3[FROWS*FS];    // 5184 B (sxy,tin)v
    __shared__ __align__(16) float   s_tmp[TILE*FS];    // 4608 B (trace,diff)v -> x^2 v
    // total 37824 B -> 4 blocks/CU

    const int tx  = threadIdx.x;          // 0..31 (time)
    const int ty  = threadIdx.y;          // 0..15 (freq)
    const int tid = ty * 32 + tx;         // 0..511
    const int ryh = tid >> 4;             // 0..31  hpass row
    const int mch = tid & 15;             // 0..15  hpass col-pair
    const int t0  = blockIdx.x * TILE;
    const int f0  = blockIdx.y * TILE;
    const int b   = blockIdx.z;

    // 1D gaussian = normalized middle row of the separable 5x5 kernel
    float r0 = gk_in[10], r1 = gk_in[11], r2 = gk_in[12], r3 = gk_in[13], r4 = gk_in[14];
    float winv = __builtin_amdgcn_rcpf(r0 + r1 + r2 + r3 + r4);
    const float w[5] = {r0*winv, r1*winv, r2*winv, r3*winv, r4*winv};
    const __half2 wh2[5] = {pack_h2(w[0],w[0]), pack_h2(w[1],w[1]), pack_h2(w[2],w[2]),
                            pack_h2(w[3],w[3]), pack_h2(w[4],w[4])};
    const __half2 h2z    = pack_h2(0.f, 0.f);
    const __half2 two    = pack_h2(2.f, 2.f);
    const __half2 eighth = pack_h2(0.125f, 0.125f);

    // row-pair pk vertical pass: 2 output rows per item, taps shared.
    // out row R = sum_i w[i]*src[R+i]; item covers R=2rg, 2rg+1 (reads rows 2rg..2rg+5)
    auto vpass2 = [&](const __half2* src, __half2* dst) {
        const uint2* s = (const uint2*)src;
        uint2* d = (uint2*)dst;
        for (int idx = tid; idx < 16 * FH2; idx += NTHR) {   // 288 items
            int rg = idx / FH2, p = idx - rg * FH2;
            int base = 2 * rg * FH2 + p;
            uint2 vv[6];
            #pragma unroll
            for (int i = 0; i < 6; ++i) vv[i] = s[base + i * FH2];
            __half2 a0 = h2z, a1 = h2z, b0 = h2z, b1 = h2z;
            #pragma unroll
            for (int i = 0; i < 5; ++i) {
                a0 = __hfma2(wh2[i], u2h(vv[i].x),     a0);
                a1 = __hfma2(wh2[i], u2h(vv[i].y),     a1);
                b0 = __hfma2(wh2[i], u2h(vv[i + 1].x), b0);
                b1 = __hfma2(wh2[i], u2h(vv[i + 1].y), b1);
            }
            uint2 oa; oa.x = *(const unsigned*)&a0; oa.y = *(const unsigned*)&a1;
            uint2 ob; ob.x = *(const unsigned*)&b0; ob.y = *(const unsigned*)&b1;
            d[base] = oa;
            d[base + FH2] = ob;
        }
    };

    float acc[6][2];     // [plane][col 2mch / 2mch+1]
    #pragma unroll
    for (int k = 0; k < 6; ++k)
        #pragma unroll
        for (int s = 0; s < 2; ++s) acc[k][s] = 0.0f;

    const bool interior = (f0 >= 4) && (f0 + TILE + 4 <= F_DIM) &&
                          (t0 >= 4) && (t0 + TILE + 4 <= T_DIM);

    // ---- Phases A, B, CD1 templated on interior fast path (as round 11) ----
    auto phaseABC = [&](const float* xp, auto FASTC) {
        constexpr bool FAST = decltype(FASTC)::value;

        // ---- Phase A: load x tile + halo 4 (float2, never straddles edges) ----
        for (int idx = tid; idx < XROWS * 20; idx += NTHR) {
            int r  = idx / 20, c2 = idx - r * 20;
            float2 v;
            if (FAST) {
                v = *(const float2*)(xp + (size_t)(f0 + r - 4) * T_DIM + (t0 + c2 * 2 - 4));
            } else {
                int gf = f0 + r - 4;
                int gt = t0 + c2 * 2 - 4;
                v = make_float2(0.f, 0.f);
                if ((unsigned)gf < (unsigned)F_DIM && (unsigned)gt < (unsigned)T_DIM)
                    v = *(const float2*)(xp + (size_t)gf * T_DIM + gt);
            }
            *(float2*)&s_x[r * XS + c2 * 2] = v;
        }
        __syncthreads();

        // ---- Phase B: even-pair items (r,2m)+(r,2m+1); 38x38 u, 36x36 fields ----
        for (int q = tid; q < UROWS * 19; q += NTHR) {
            int r = q / 19, m = q - r * 19;
            const float2* x2p = (const float2*)s_x;
            int base = r * (XS/2) + m;
            float2 a0 = x2p[base],            b0 = x2p[base + 1];
            float2 a1 = x2p[base + (XS/2)],   b1 = x2p[base + (XS/2) + 1];
            float2 a2 = x2p[base + XS],       b2 = x2p[base + XS + 1];
            // shared sobel column sums
            float c0 = a2.x - a0.x, c1 = a2.y - a0.y;
            float c2c = b2.x - b0.x, c3 = b2.y - b0.y;
            float s0 = fmaf(2.f, a1.x, a0.x + a2.x);
            float s1 = fmaf(2.f, a1.y, a0.y + a2.y);
            float s2 = fmaf(2.f, b1.x, b0.x + b2.x);
            float s3 = fmaf(2.f, b1.y, b0.y + b2.y);
            float gfvA = (fmaf(2.f, c1, c0) + c2c) * 0.125f;
            float gtvA = (s2 - s0) * 0.125f;
            float gfvB = (fmaf(2.f, c2c, c1) + c3) * 0.125f;
            float gtvB = (s3 - s1) * 0.125f;

            bool rin = (r >= 1) && (r < UROWS - 1);
            int  fiA = (r - 1) * FS + 2 * m - 1;
            int  gfr = f0 + r - 3;
            bool frOK = FAST || ((unsigned)gfr < (unsigned)F_DIM);

            #pragma unroll
            for (int jj = 0; jj < 2; ++jj) {
                float gfv = jj ? gfvB : gfvA;
                float gtv = jj ? gtvB : gtvA;
                int   ccI = 2 * m + jj;
                bool  okI = true;
                if (!FAST) {
                    int gtc = t0 + ccI - 3;
                    okI = frOK & ((unsigned)gtc < (unsigned)T_DIM);
                }
                float ux = 0.f, uy = 0.f, trp = 0.f, dfp = 0.f, sxy = 0.f,
                      tin = 0.f, sf = 0.f;
                if (okI) {
                    float gte = gtv + EPSF;
                    float g2f = gfv * gfv;
                    float d2  = fmaf(gte, gte, g2f);
                    float rh  = __builtin_amdgcn_rsqf(d2);
                    ux = gte * rh;
                    uy = gfv * rh;
                    float m2 = fmaf(gtv, gtv, g2f) + EPSF;
                    trp = m2;
                    dfp = m2 * (ux - uy) * (ux + uy);
                    sxy = m2 * ux * uy;
                    tin = __builtin_amdgcn_rcpf(1.0f + fabsf(gtv));
                    sf  = fabsf(gfv);
                }
                s_u[r * US + ccI + 1] = pack_h2(ux, uy);   // +1 col shift
                bool pv = rin && (jj ? (m <= 17) : (m >= 1));
                if (pv) {
                    int fi = fiA + jj;
                    s_P0[fi] = pack_h2(trp, dfp);
                    s_P1[fi] = pack_h2(sxy, tin);
                    s_P2[fi] = pack_h2(sf, 0.f);   // .y = cv, filled in Phase C
                }
            }
        }
        __syncthreads();

        // ---- Slot CD1: Phase C pairs (u sobel -> P2.y) + v(P0->tmp) + v(P1->P3) ----
        for (int q = tid; q < FROWS * 18; q += NTHR) {
            int r = q / 18, m = q - r * 18;
            const uint2* su2 = (const uint2*)s_u;
            int base = r * (US/2) + m;
            uint2 q00 = su2[base],              q01 = su2[base + 1],              q02 = su2[base + 2];
            uint2 q10 = su2[base + (US/2)],     q11 = su2[base + (US/2) + 1],     q12 = su2[base + (US/2) + 2];
            uint2 q20 = su2[base + US],         q21 = su2[base + US + 1],         q22 = su2[base + US + 2];
            __half2 l1 = __hadd2(u2h(q00.y), u2h(q20.y)); l1 = __hfma2(two, u2h(q10.y), l1);
            __half2 l2 = __hadd2(u2h(q01.x), u2h(q21.x)); l2 = __hfma2(two, u2h(q11.x), l2);
            __half2 l3 = __hadd2(u2h(q01.y), u2h(q21.y)); l3 = __hfma2(two, u2h(q11.y), l3);
            __half2 l4 = __hadd2(u2h(q02.x), u2h(q22.x)); l4 = __hfma2(two, u2h(q12.x), l4);
            __half2 tA = __hadd2(u2h(q00.y), u2h(q01.y)); tA = __hfma2(two, u2h(q01.x), tA);
            __half2 bA = __hadd2(u2h(q20.y), u2h(q21.y)); bA = __hfma2(two, u2h(q21.x), bA);
            __half2 tB = __hadd2(u2h(q01.x), u2h(q02.x)); tB = __hfma2(two, u2h(q01.y), tB);
            __half2 bB = __hadd2(u2h(q21.x), u2h(q22.x)); bB = __hfma2(two, u2h(q21.y), bB);
            __half2 dxA = __hmul2(__hsub2(l3, l1), eighth);
            __half2 dyA = __hmul2(__hsub2(bA, tA), eighth);
            __half2 dxB = __hmul2(__hsub2(l4, l2), eighth);
            __half2 dyB = __hmul2(__hsub2(bB, tB), eighth);

            int gfr = f0 + r - 2;
            bool frOK = FAST || ((unsigned)gfr < (unsigned)F_DIM);
            #pragma unroll
            for (int jj = 0; jj < 2; ++jj) {
                float2 fx = __half22float2(jj ? dxB : dxA);
                float2 fy = __half22float2(jj ? dyB : dyA);
                float cv = __builtin_amdgcn_sqrtf(
                    fmaf(fx.x, fx.x, fmaf(fx.y, fx.y,
                    fmaf(fy.x, fy.x, fy.y * fy.y))) + EPSF);
                int ccI = 2 * m + jj;
                if (!FAST) {
                    int gtc = t0 + ccI - 2;
                    if (!(frOK & ((unsigned)gtc < (unsigned)T_DIM))) cv = 0.f;
                }
                ((__half*)s_P2)[2 * (r * FS + ccI) + 1] = __float2half_rn(cv);
            }
        }
        vpass2(s_P0, (__half2*)s_tmp);   // j0 vertical: (trace,diff)
        vpass2(s_P1, s_P3);              // j1 vertical: (sxy,tin)
        __syncthreads();
    };

    for (int c = 0; c < C_DIM; ++c) {
        if (c) __syncthreads();   // protect LDS reuse (c==1 only)

        const float* xp = x_in + (size_t)(b * C_DIM + c) * F_DIM * T_DIM;
        if (interior) phaseABC(xp, BoolC<true>{});
        else          phaseABC(xp, BoolC<false>{});

        __half2* tmp_h2 = (__half2*)s_tmp;

        // ====== Slot D23: j0h+j1h col-pair + entropy/temporal ; v(P2->P0) ; v(u->P1) ======
        {
            // j0h: trace/diff (f32 accumulation), cols 2mch, 2mch+1
            const uint2* t2 = (const uint2*)tmp_h2;
            uint2 ta = t2[ryh * FH2 + mch], tb = t2[ryh * FH2 + mch + 1],
                  tc = t2[ryh * FH2 + mch + 2];
            float2 e0 = __half22float2(u2h(ta.x)), e1 = __half22float2(u2h(ta.y));
            float2 e2 = __half22float2(u2h(tb.x)), e3 = __half22float2(u2h(tb.y));
            float2 e4 = __half22float2(u2h(tc.x)), e5 = __half22float2(u2h(tc.y));
            float trc[2], dfc[2];
            trc[0] = w[0]*e0.x + w[1]*e1.x + w[2]*e2.x + w[3]*e3.x + w[4]*e4.x;
            dfc[0] = w[0]*e0.y + w[1]*e1.y + w[2]*e2.y + w[3]*e3.y + w[4]*e4.y;
            trc[1] = w[0]*e1.x + w[1]*e2.x + w[2]*e3.x + w[3]*e4.x + w[4]*e5.x;
            dfc[1] = w[0]*e1.y + w[1]*e2.y + w[2]*e3.y + w[3]*e4.y + w[4]*e5.y;

            // j1h: (vxy,tp) h2 accumulation, cols 2mch, 2mch+1
            const uint2* p3q = (const uint2*)s_P3;
            uint2 pa = p3q[ryh * FH2 + mch], pb = p3q[ryh * FH2 + mch + 1],
                  pc = p3q[ryh * FH2 + mch + 2];
            __half2 aA = h2z, aB = h2z;
            aA = __hfma2(wh2[0], u2h(pa.x), aA);
            aA = __hfma2(wh2[1], u2h(pa.y), aA);
            aA = __hfma2(wh2[2], u2h(pb.x), aA);
            aA = __hfma2(wh2[3], u2h(pb.y), aA);
            aA = __hfma2(wh2[4], u2h(pc.x), aA);
            aB = __hfma2(wh2[0], u2h(pa.y), aB);
            aB = __hfma2(wh2[1], u2h(pb.x), aB);
            aB = __hfma2(wh2[2], u2h(pb.y), aB);
            aB = __hfma2(wh2[3], u2h(pc.x), aB);
            aB = __hfma2(wh2[4], u2h(pc.y), aB);
            float2 vc[2] = {__half22float2(aA), __half22float2(aB)};
            #pragma unroll
            for (int col = 0; col < 2; ++col) {
                float trace = trc[col], diff = dfc[col];
                float2 v = vc[col];
                float disc  = __builtin_amdgcn_sqrtf(
                                  fmaxf(diff * diff + 4.f * v.x * v.x, 0.f) + EPSF);
                float l1 = fmaxf(0.5f * (trace + disc), EPSF);
                float l2 = fmaxf(0.5f * (trace - disc), EPSF);
                float inv = __builtin_amdgcn_rcpf(l1 + l2 + EPSF);
                float p1 = l1 * inv, p2 = l2 * inv;
                // v_log_f32 IS log2 — matches reference's ln(p)/ln(2)
                float ent = -(p1 * __builtin_amdgcn_logf(p1 + EPSF)
                            + p2 * __builtin_amdgcn_logf(p2 + EPSF));
                acc[0][col] += 0.5f * clamp01(ent);
                acc[4][col] += 0.5f * clamp01(v.y);
            }

            vpass2(s_P2, s_P0);          // j2 vertical: (sf,cv) -> P0
            {
                // j3 vertical: u -> P1, row-pair items (out rows 2rg,2rg+1)
                const uint2* su2 = (const uint2*)s_u;
                uint2* dP1 = (uint2*)s_P1;
                for (int idx = tid; idx < 16 * FH2; idx += NTHR) {
                    int rg = idx / FH2, p = idx - rg * FH2;
                    const uint2* sp = su2 + (2 * rg + 1) * (US/2) + 1 + p;
                    uint2 vv[6];
                    #pragma unroll
                    for (int i = 0; i < 6; ++i) vv[i] = sp[i * (US/2)];
                    __half2 a0 = h2z, a1 = h2z, b0 = h2z, b1 = h2z;
                    #pragma unroll
                    for (int i = 0; i < 5; ++i) {
                        a0 = __hfma2(wh2[i], u2h(vv[i].x),     a0);
                        a1 = __hfma2(wh2[i], u2h(vv[i].y),     a1);
                        b0 = __hfma2(wh2[i], u2h(vv[i + 1].x), b0);
                        b1 = __hfma2(wh2[i], u2h(vv[i + 1].y), b1);
                    }
                    uint2 oa; oa.x = *(const unsigned*)&a0; oa.y = *(const unsigned*)&a1;
                    uint2 ob; ob.x = *(const unsigned*)&b0; ob.y = *(const unsigned*)&b1;
                    dP1[2 * rg * FH2 + p] = oa;
                    dP1[(2 * rg + 1) * FH2 + p] = ob;
                }
            }
        }
        __syncthreads();

        // ====== Slot D45: j2h (P0) + j3h (P1) col-pair ; v(x^2 -> tmp) ======
        {
            const uint2* p0q = (const uint2*)s_P0;
            uint2 qa = p0q[ryh * FH2 + mch], qb = p0q[ryh * FH2 + mch + 1],
                  qc = p0q[ryh * FH2 + mch + 2];
            __half2 sA = h2z, sB = h2z;
            sA = __hfma2(wh2[0], u2h(qa.x), sA);
            sA = __hfma2(wh2[1], u2h(qa.y), sA);
            sA = __hfma2(wh2[2], u2h(qb.x), sA);
            sA = __hfma2(wh2[3], u2h(qb.y), sA);
            sA = __hfma2(wh2[4], u2h(qc.x), sA);
            sB = __hfma2(wh2[0], u2h(qa.y), sB);
            sB = __hfma2(wh2[1], u2h(qb.x), sB);
            sB = __hfma2(wh2[2], u2h(qb.y), sB);
            sB = __hfma2(wh2[3], u2h(qc.x), sB);
            sB = __hfma2(wh2[4], u2h(qc.y), sB);
            float2 s0 = __half22float2(sA), s1 = __half22float2(sB);   // (sp, cvs)
            acc[5][0] += 0.5f * clamp01(s0.x);  acc[2][0] += 0.5f * s0.y;
            acc[5][1] += 0.5f * clamp01(s1.x);  acc[2][1] += 0.5f * s1.y;

            const uint2* p1q = (const uint2*)s_P1;
            uint2 ra = p1q[ryh * FH2 + mch], rb = p1q[ryh * FH2 + mch + 1],
                  rc = p1q[ryh * FH2 + mch + 2];
            __half2 uA = h2z, uB = h2z;
            uA = __hfma2(wh2[0], u2h(ra.x), uA);
            uA = __hfma2(wh2[1], u2h(ra.y), uA);
            uA = __hfma2(wh2[2], u2h(rb.x), uA);
            uA = __hfma2(wh2[3], u2h(rb.y), uA);
            uA = __hfma2(wh2[4], u2h(rc.x), uA);
            uB = __hfma2(wh2[0], u2h(ra.y), uB);
            uB = __hfma2(wh2[1], u2h(rb.x), uB);
            uB = __hfma2(wh2[2], u2h(rb.y), uB);
            uB = __hfma2(wh2[3], u2h(rc.x), uB);
            uB = __hfma2(wh2[4], u2h(rc.y), uB);
            float2 u0 = __half22float2(uA), u1 = __half22float2(uB);   // (ua, va)
            acc[1][0] += 0.5f * clamp01(
                __builtin_amdgcn_sqrtf(u0.x * u0.x + u0.y * u0.y + EPSF));
            acc[1][1] += 0.5f * clamp01(
                __builtin_amdgcn_sqrtf(u1.x * u1.x + u1.y * u1.y + EPSF));

            // j4 vertical: x^2 -> tmp, row-pair items (out rows 2rg,2rg+1)
            const float2* sx2 = (const float2*)s_x;
            float2* dt2 = (float2*)s_tmp;
            for (int idx = tid; idx < 16 * FH2; idx += NTHR) {
                int rg = idx / FH2, p = idx - rg * FH2;
                const float2* sp = sx2 + (2 * rg + 2) * (XS/2) + 1 + p;
                float2 sq[6];
                #pragma unroll
                for (int i = 0; i < 6; ++i) {
                    float2 v = sp[i * (XS/2)];
                    sq[i] = make_float2(v.x * v.x, v.y * v.y);
                }
                float aA = 0.f, bA = 0.f, aB = 0.f, bB = 0.f;
                #pragma unroll
                for (int i = 0; i < 5; ++i) {
                    aA = fmaf(w[i], sq[i].x,     aA);
                    bA = fmaf(w[i], sq[i].y,     bA);
                    aB = fmaf(w[i], sq[i + 1].x, aB);
                    bB = fmaf(w[i], sq[i + 1].y, bB);
                }
                dt2[2 * rg * FH2 + p] = make_float2(aA, bA);
                dt2[(2 * rg + 1) * FH2 + p] = make_float2(aB, bB);
            }
        }
        __syncthreads();

        // ====== Slot D6: j4h (le) col-pair + harmonic epilogue ======
        {
            const float2* tf = (const float2*)s_tmp;   // element p = x^2v cols 2p,2p+1
            float2 q0 = tf[ryh * FH2 + mch], q1 = tf[ryh * FH2 + mch + 1],
                   q2 = tf[ryh * FH2 + mch + 2];
            float le0 = w[0]*q0.x + w[1]*q0.y + w[2]*q1.x + w[3]*q1.y + w[4]*q2.x;
            float le1 = w[0]*q0.y + w[1]*q1.x + w[2]*q1.y + w[3]*q2.x + w[4]*q2.y;
            const float2* sxf = (const float2*)s_x;
            float2 xm  = sxf[(ryh + 1) * (XS/2) + mch + 2];
            float2 x0v = sxf[(ryh + 4) * (XS/2) + mch + 2];
            float2 xpv = sxf[(ryh + 7) * (XS/2) + mch + 2];
            float hA = fabsf(2.f * x0v.x - xm.x - xpv.x);
            float hB = fabsf(2.f * x0v.y - xm.y - xpv.y);
            acc[3][0] += 0.5f * clamp01(hA * __builtin_amdgcn_rcpf(le0 + EPSF));
            acc[3][1] += 0.5f * clamp01(hB * __builtin_amdgcn_rcpf(le1 + EPSF));
        }
    }

    // ---- write 6 output planes: one float2 per plane per thread, coalesced ----
    const size_t plane = (size_t)B_DIM * F_DIM * T_DIM;
    const size_t base  = (size_t)b * F_DIM * T_DIM
                       + (size_t)(f0 + ryh) * T_DIM + t0 + 2 * mch;
    #pragma unroll
    for (int k = 0; k < 6; ++k)
        *(float2*)(out + k * plane + base) = make_float2(acc[k][0], acc[k][1]);
}

extern "C" void kernel_launch(void* const* d_in, const int* in_sizes, int n_in,
                              void* d_out, int out_size, void* d_ws, size_t ws_size,
                              hipStream_t stream) {
    const float* x  = (const float*)d_in[0];
    const float* gk = (const float*)d_in[1];
    float* out = (float*)d_out;
    dim3 grid(T_DIM / TILE, F_DIM / TILE, B_DIM);   // 64 x 8 x 8 = 4096 blocks
    dim3 block(32, 16);                             // 512 threads = 8 waves
    audio_struct_fused<<<grid, block, 0, stream>>>(x, gk, out);
}